// Round 10
// baseline (220.873 us; speedup 1.0000x reference)
//
#include <hip/hip_runtime.h>
#include <cstdint>
#include <cstddef>

typedef __bf16 bf16x8 __attribute__((ext_vector_type(8)));
typedef __bf16 bf16x2v __attribute__((ext_vector_type(2)));
typedef unsigned short u16;
typedef u16 u16x8v __attribute__((ext_vector_type(8)));
typedef float  f32x4  __attribute__((ext_vector_type(4)));
typedef unsigned int u32;

#define MFMA16(a, b, c) __builtin_amdgcn_mfma_f32_16x16x32_bf16((a), (b), (c), 0, 0, 0)
#define ASYNC16(g, l)                                                              \
  __builtin_amdgcn_global_load_lds(                                                \
      (const __attribute__((address_space(1))) unsigned int*)(g),                  \
      (__attribute__((address_space(3))) unsigned int*)(l), 16, 0, 0)

__device__ __forceinline__ u16 f2bf(float f) {
  unsigned u = __builtin_bit_cast(unsigned, f);
  u += 0x7fffu + ((u >> 16) & 1u);
  return (u16)(u >> 16);
}

// packed fp32x2 -> bf16x2 (RNE) via hardware cvt
__device__ __forceinline__ u32 cvt2(float a, float b) {
  bf16x2v t;
  t[0] = (__bf16)a;
  t[1] = (__bf16)b;
  return __builtin_bit_cast(u32, t);
}

#define SEQ 2048
#define CH  1024
#define NH  16
#define HD  64
// log2(e) / sqrt(64) folded into stored Q so softmax uses exp2
#define QSCALE 0.18033688011112042f

// ------------- fused prep: cast x + transpose-cast qkv_w + proj_w -------------
__global__ void __launch_bounds__(256) prep_kernel(const float* __restrict__ x,
                                                   const float* __restrict__ qkv_w,
                                                   const float* __restrict__ proj_w,
                                                   u16* __restrict__ xb,
                                                   u16* __restrict__ wqkvt,
                                                   u16* __restrict__ wprojt) {
  __shared__ u16 t[64][68];
  int bx = blockIdx.x;
  int tx = threadIdx.x;
  if (bx < 4096) {
    int i = bx * 256 + tx;
    float4 v = ((const float4*)x)[i];
    ushort4 o;
    o.x = f2bf(v.x); o.y = f2bf(v.y); o.z = f2bf(v.z); o.w = f2bf(v.w);
    ((ushort4*)xb)[i] = o;
    return;
  }
  const float* in; u16* out; int R, C, c0, r0;
  if (bx < 4096 + 768) {
    int i = bx - 4096;
    in = qkv_w; out = wqkvt; R = 1024; C = 3072;
    c0 = (i % 48) * 64; r0 = (i / 48) * 64;
  } else {
    int i = bx - 4864;
    in = proj_w; out = wprojt; R = 1024; C = 1024;
    c0 = (i % 16) * 64; r0 = (i / 16) * 64;
  }
  int rr = tx >> 6, cc = tx & 63;
#pragma unroll
  for (int i = 0; i < 16; ++i) {
    int r = i * 4 + rr;
    t[r][cc] = f2bf(in[(size_t)(r0 + r) * C + c0 + cc]);
  }
  __syncthreads();
#pragma unroll
  for (int i = 0; i < 16; ++i) {
    int r = i * 4 + rr;
    out[(size_t)(c0 + r) * R + r0 + cc] = t[cc][r];
  }
}

// ------------- transpose V slice of qkv (per b,h: (N x D) -> (D x N)) -------------
__global__ void __launch_bounds__(256) tv_kernel(const u16* __restrict__ qkv,
                                                 u16* __restrict__ vt) {
  __shared__ u16 t[64][68];
  int n0 = blockIdx.x * 64;
  int bh = blockIdx.y;
  int b = bh >> 4, h = bh & 15;
  int tx = threadIdx.x;
  int rr = tx >> 6, cc = tx & 63;
  const u16* src = qkv + (size_t)(b * SEQ) * 3072 + 2048 + h * 64;
#pragma unroll
  for (int i = 0; i < 16; ++i) {
    int n = i * 4 + rr;
    t[n][cc] = src[(size_t)(n0 + n) * 3072 + cc];
  }
  __syncthreads();
  u16* dst = vt + (size_t)bh * 64 * SEQ;
#pragma unroll
  for (int i = 0; i < 16; ++i) {
    int d = i * 4 + rr;
    dst[(size_t)d * SEQ + n0 + cc] = t[cc][d];
  }
}

// ------------- GEMM: C(MxN) = A(MxK,bf16) @ Bt(NxK,bf16)^T + bias -------------
// Tile: (MT*32) x 128. MT=4 -> 128x128 (qkv gemm), MT=2 -> 64x128 (proj).
// mode 0: write bf16, scale cols<1024 by QSCALE.  mode 1: write fp32.
template <int MT>
__global__ void __launch_bounds__(256) gemm_kernel(const u16* __restrict__ A,
                                                   const u16* __restrict__ Bt,
                                                   const float* __restrict__ bias,
                                                   u16* __restrict__ outb,
                                                   float* __restrict__ outf,
                                                   int N, int K, int mode) {
  constexpr int R = MT * 32;
  __shared__ alignas(16) u16 As[R * 32];
  __shared__ alignas(16) u16 Bs[128 * 32];
  int tid = threadIdx.x;
  int lane = tid & 63, wave = tid >> 6;
  int wm = wave >> 1, wn = wave & 1;
  int qr = lane & 15, quad = lane >> 4;
  size_t rowA = (size_t)blockIdx.y * R;
  size_t rowB = (size_t)blockIdx.x * 128;
  int r0 = tid >> 2, c0 = (tid & 3) << 3;

  const u16* a0 = A + (rowA + r0) * K + c0;
  const u16* b0 = Bt + (rowB + r0) * K + c0;
  size_t step64 = (size_t)64 * K;
  u16* lA = &As[r0 * 32 + c0];
  u16* lB = &Bs[r0 * 32 + c0];

  f32x4 acc[MT][4];
#pragma unroll
  for (int mt = 0; mt < MT; ++mt)
#pragma unroll
    for (int nt = 0; nt < 4; ++nt) acc[mt][nt] = (f32x4){0.f, 0.f, 0.f, 0.f};

  for (int k0 = 0; k0 < K; k0 += 32) {
#pragma unroll
    for (int i = 0; i < R / 64; ++i)
      ASYNC16(a0 + k0 + i * step64, lA + i * 64 * 32);
    ASYNC16(b0 + k0, lB);
    ASYNC16(b0 + k0 + step64, lB + 64 * 32);
    __syncthreads();
    bf16x8 af[MT], bfr[4];
#pragma unroll
    for (int mt = 0; mt < MT; ++mt)
      af[mt] = *(const bf16x8*)&As[(wm * (MT * 16) + mt * 16 + qr) * 32 + quad * 8];
#pragma unroll
    for (int nt = 0; nt < 4; ++nt)
      bfr[nt] = *(const bf16x8*)&Bs[(wn * 64 + nt * 16 + qr) * 32 + quad * 8];
#pragma unroll
    for (int mt = 0; mt < MT; ++mt)
#pragma unroll
      for (int nt = 0; nt < 4; ++nt)
        acc[mt][nt] = MFMA16(af[mt], bfr[nt], acc[mt][nt]);
    __syncthreads();
  }

#pragma unroll
  for (int nt = 0; nt < 4; ++nt) {
    int col = (int)rowB + wn * 64 + nt * 16 + qr;
    float bv = bias[col];
#pragma unroll
    for (int mt = 0; mt < MT; ++mt) {
      size_t row = rowA + wm * (MT * 16) + mt * 16 + quad * 4;
#pragma unroll
      for (int r = 0; r < 4; ++r) {
        float v = acc[mt][nt][r] + bv;
        if (mode == 0) {
          if (col < 1024) v *= QSCALE;
          outb[(row + r) * N + col] = f2bf(v);
        } else {
          outf[(row + r) * N + col] = v;
        }
      }
    }
  }
}

// ------------- flash attention v8: 128 Q rows/block, 4 waves x 32 rows -------------
// Latency-chain fix: P buffer DOUBLE-BUFFERED per wave (parity = subphase) so the
// exp2/cvt/ds_write of subphase i+1 overlaps PV(i)'s pf-read stall. K-tile (128x64)
// LDS dbuf (BK=128, 16 barriers); V fragments read DIRECTLY from global (L2-resident,
// chain tail -> latency hidden behind QK/exp). LDS 64KB -> 2 blocks/CU.
// QK^T transposed (A=K, B=Q); denominator on the MFMA pipe via B=ones.
__global__ void __launch_bounds__(256) attn_kernel(const u16* __restrict__ qkv,
                                                   const u16* __restrict__ vt,
                                                   u16* __restrict__ out) {
  __shared__ alignas(16) u16 kbuf[2][128 * 64];
  __shared__ alignas(16) u16 pbuf[4][2][32 * 64];
  int bh = blockIdx.x;
  int b = bh >> 4, h = bh & 15;
  int m0 = blockIdx.y * 128;
  int tid = threadIdx.x;
  int lane = tid & 63, wave = tid >> 6;
  int qr = lane & 15, quad = lane >> 4;

  const u16* kbase = qkv + (size_t)(b * SEQ) * 3072 + 1024 + h * 64;  // K rows, stride 3072
  const u16* vtbase = vt + (size_t)bh * 64 * SEQ;                     // Vt rows, stride 2048

  // K staging: 4 instrs/wave; rows wave*32 + i*8 + (lane>>3); chunk swizzle ^(row&7)
  int klr = lane >> 3;
  int kcs = (lane & 7) ^ klr;

  // ---- Q fragments (32 rows per wave) ----
  const u16* qbase = qkv + (size_t)(b * SEQ + m0 + wave * 32) * 3072 + h * 64;
  bf16x8 qf[2][2];
#pragma unroll
  for (int mt = 0; mt < 2; ++mt)
#pragma unroll
    for (int ks = 0; ks < 2; ++ks)
      qf[mt][ks] = *(const bf16x8*)&qbase[(size_t)(mt * 16 + qr) * 3072 + ks * 32 + quad * 8];

  const bf16x8 vone = __builtin_bit_cast(bf16x8, (u16x8v)((u16)0x3F80));

  f32x4 o[2][4], l5[2];
#pragma unroll
  for (int mt = 0; mt < 2; ++mt) {
    l5[mt] = (f32x4){0.f, 0.f, 0.f, 0.f};
#pragma unroll
    for (int dt = 0; dt < 4; ++dt) o[mt][dt] = (f32x4){0.f, 0.f, 0.f, 0.f};
  }

  auto stage = [&](int buf, int n0) {
#pragma unroll
    for (int i = 0; i < 4; ++i) {
      int kr = wave * 32 + i * 8 + klr;
      ASYNC16(kbase + (size_t)(n0 + kr) * 3072 + kcs * 8,
              &kbuf[buf][(wave * 32 + i * 8) * 64 + lane * 8]);
    }
  };

  stage(0, 0);

  for (int t = 0; t < 16; ++t) {
    int cur = t & 1;
    __syncthreads();  // staging of kbuf[cur] complete; prev reads of kbuf[cur^1] done

    if (t + 1 < 16) stage(cur ^ 1, (t + 1) * 128);

#pragma unroll
    for (int sp = 0; sp < 2; ++sp) {
      const u16* kb = &kbuf[cur][sp * 64 * 64];
      u16* pw = &pbuf[wave][sp][0];

      // V fragments straight from global (L2): keys t*128 + sp*64 + ks*32 + quad*8
      bf16x8 vf[4][2];
#pragma unroll
      for (int dt = 0; dt < 4; ++dt)
#pragma unroll
        for (int ks = 0; ks < 2; ++ks)
          vf[dt][ks] = *(const bf16x8*)&vtbase[(size_t)(dt * 16 + qr) * 2048 + t * 128 +
                                               sp * 64 + ks * 32 + quad * 8];

      // S^T = K.Q^T : lane holds m = qr, n = nt*16 + quad*4 + r (4 consecutive keys)
      bf16x8 kf[4][2];
#pragma unroll
      for (int nt = 0; nt < 4; ++nt)
#pragma unroll
        for (int ks = 0; ks < 2; ++ks)
          kf[nt][ks] =
              *(const bf16x8*)&kb[(nt * 16 + qr) * 64 + (((ks * 4 + quad) ^ (qr & 7)) << 3)];

#pragma unroll
      for (int mt = 0; mt < 2; ++mt)
#pragma unroll
        for (int nt = 0; nt < 4; ++nt) {
          f32x4 z = (f32x4){0.f, 0.f, 0.f, 0.f};
          z = MFMA16(kf[nt][0], qf[mt][0], z);
          z = MFMA16(kf[nt][1], qf[mt][1], z);
          float p0 = __builtin_amdgcn_exp2f(z[0]);
          float p1 = __builtin_amdgcn_exp2f(z[1]);
          float p2 = __builtin_amdgcn_exp2f(z[2]);
          float p3 = __builtin_amdgcn_exp2f(z[3]);
          uint2 pk;
          pk.x = cvt2(p0, p1);
          pk.y = cvt2(p2, p3);
          int nb = nt * 16 + quad * 4;
          int addr = (mt * 16 + qr) * 64 + ((((nb >> 3) ^ (qr & 7)) << 3) | (nb & 7));
          *(uint2*)&pw[addr] = pk;
        }

      bf16x8 pf[2][2];
#pragma unroll
      for (int mt = 0; mt < 2; ++mt)
#pragma unroll
        for (int ks = 0; ks < 2; ++ks)
          pf[mt][ks] =
              *(const bf16x8*)&pw[(mt * 16 + qr) * 64 + (((ks * 4 + quad) ^ (qr & 7)) << 3)];

#pragma unroll
      for (int mt = 0; mt < 2; ++mt) {
#pragma unroll
        for (int dt = 0; dt < 4; ++dt) {
          o[mt][dt] = MFMA16(pf[mt][0], vf[dt][0], o[mt][dt]);
          o[mt][dt] = MFMA16(pf[mt][1], vf[dt][1], o[mt][dt]);
        }
        l5[mt] = MFMA16(pf[mt][0], vone, l5[mt]);
        l5[mt] = MFMA16(pf[mt][1], vone, l5[mt]);
      }
    }
  }

  // l5[mt][r] already holds the denominator for exactly the rows this lane stores.
  u16* obase = out + (size_t)(b * SEQ + m0 + wave * 32) * CH + h * 64;
#pragma unroll
  for (int mt = 0; mt < 2; ++mt)
#pragma unroll
    for (int r = 0; r < 4; ++r) {
      float inv = 1.0f / l5[mt][r];
#pragma unroll
      for (int dt = 0; dt < 4; ++dt)
        obase[(size_t)(mt * 16 + quad * 4 + r) * CH + dt * 16 + qr] = f2bf(o[mt][dt][r] * inv);
    }
}

extern "C" void kernel_launch(void* const* d_in, const int* in_sizes, int n_in,
                              void* d_out, int out_size, void* d_ws, size_t ws_size,
                              hipStream_t stream) {
  const float* x      = (const float*)d_in[0];
  const float* qkv_w  = (const float*)d_in[1];
  const float* qkv_b  = (const float*)d_in[2];
  const float* proj_w = (const float*)d_in[3];
  const float* proj_b = (const float*)d_in[4];
  float* out = (float*)d_out;

  char* w = (char*)d_ws;
  // ws layout (42 MB):
  //   qkv_bf : 4096x3072 bf16 = 25165824 B
  //   xb     : 4096x1024 bf16 =  8388608 B  (reused as attn_bf after gemm1)
  //   wprojt : 1024x1024 bf16 =  2097152 B
  //   wqkvt  : 3072x1024 bf16 (6 MB) region sized 8 MB, reused as vt (B,H,D,N)
  u16* qkv_bf = (u16*)w;
  u16* xb     = (u16*)(w + 25165824);
  u16* wprojt = (u16*)(w + 25165824 + 8388608);
  u16* wqkvt  = (u16*)(w + 25165824 + 8388608 + 2097152);
  u16* attn_bf = xb;
  u16* vt      = wqkvt;

  prep_kernel<<<5120, 256, 0, stream>>>(x, qkv_w, proj_w, xb, wqkvt, wprojt);
  // qkv = x @ qkv_w + b  (bf16 out; Q cols pre-scaled by log2e/8)
  gemm_kernel<4><<<dim3(24, 32), 256, 0, stream>>>(xb, wqkvt, qkv_b, qkv_bf, nullptr, 3072, 1024, 0);
  tv_kernel<<<dim3(32, 32), 256, 0, stream>>>(qkv_bf, vt);
  attn_kernel<<<dim3(32, 16), 256, 0, stream>>>(qkv_bf, vt, attn_bf);
  // out = attn @ proj_w + b (fp32); 64x128 tile -> 512 blocks
  gemm_kernel<2><<<dim3(8, 64), 256, 0, stream>>>(attn_bf, wprojt, proj_b, nullptr, out, 1024, 1024, 1);
}

// Round 11
// 196.788 us; speedup vs baseline: 1.1224x; 1.1224x over previous
//
#include <hip/hip_runtime.h>
#include <cstdint>
#include <cstddef>

typedef __bf16 bf16x8 __attribute__((ext_vector_type(8)));
typedef __bf16 bf16x2v __attribute__((ext_vector_type(2)));
typedef unsigned short u16;
typedef u16 u16x8v __attribute__((ext_vector_type(8)));
typedef float  f32x4  __attribute__((ext_vector_type(4)));
typedef unsigned int u32;

#define MFMA16(a, b, c) __builtin_amdgcn_mfma_f32_16x16x32_bf16((a), (b), (c), 0, 0, 0)
#define ASYNC16(g, l)                                                              \
  __builtin_amdgcn_global_load_lds(                                                \
      (const __attribute__((address_space(1))) unsigned int*)(g),                  \
      (__attribute__((address_space(3))) unsigned int*)(l), 16, 0, 0)

__device__ __forceinline__ u16 f2bf(float f) {
  unsigned u = __builtin_bit_cast(unsigned, f);
  u += 0x7fffu + ((u >> 16) & 1u);
  return (u16)(u >> 16);
}

// packed fp32x2 -> bf16x2 (RNE) via hardware cvt
__device__ __forceinline__ u32 cvt2(float a, float b) {
  bf16x2v t;
  t[0] = (__bf16)a;
  t[1] = (__bf16)b;
  return __builtin_bit_cast(u32, t);
}

#define SEQ 2048
#define CH  1024
#define NH  16
#define HD  64
// log2(e) / sqrt(64) folded into stored Q so softmax uses exp2
#define QSCALE 0.18033688011112042f

// ------------- fused prep: cast x + transpose-cast qkv_w + proj_w -------------
__global__ void __launch_bounds__(256) prep_kernel(const float* __restrict__ x,
                                                   const float* __restrict__ qkv_w,
                                                   const float* __restrict__ proj_w,
                                                   u16* __restrict__ xb,
                                                   u16* __restrict__ wqkvt,
                                                   u16* __restrict__ wprojt) {
  __shared__ u16 t[64][68];
  int bx = blockIdx.x;
  int tx = threadIdx.x;
  if (bx < 4096) {
    int i = bx * 256 + tx;
    float4 v = ((const float4*)x)[i];
    ushort4 o;
    o.x = f2bf(v.x); o.y = f2bf(v.y); o.z = f2bf(v.z); o.w = f2bf(v.w);
    ((ushort4*)xb)[i] = o;
    return;
  }
  const float* in; u16* out; int R, C, c0, r0;
  if (bx < 4096 + 768) {
    int i = bx - 4096;
    in = qkv_w; out = wqkvt; R = 1024; C = 3072;
    c0 = (i % 48) * 64; r0 = (i / 48) * 64;
  } else {
    int i = bx - 4864;
    in = proj_w; out = wprojt; R = 1024; C = 1024;
    c0 = (i % 16) * 64; r0 = (i / 16) * 64;
  }
  int rr = tx >> 6, cc = tx & 63;
#pragma unroll
  for (int i = 0; i < 16; ++i) {
    int r = i * 4 + rr;
    t[r][cc] = f2bf(in[(size_t)(r0 + r) * C + c0 + cc]);
  }
  __syncthreads();
#pragma unroll
  for (int i = 0; i < 16; ++i) {
    int r = i * 4 + rr;
    out[(size_t)(c0 + r) * R + r0 + cc] = t[cc][r];
  }
}

// ------------- transpose V slice of qkv (per b,h: (N x D) -> (D x N)) -------------
__global__ void __launch_bounds__(256) tv_kernel(const u16* __restrict__ qkv,
                                                 u16* __restrict__ vt) {
  __shared__ u16 t[64][68];
  int n0 = blockIdx.x * 64;
  int bh = blockIdx.y;
  int b = bh >> 4, h = bh & 15;
  int tx = threadIdx.x;
  int rr = tx >> 6, cc = tx & 63;
  const u16* src = qkv + (size_t)(b * SEQ) * 3072 + 2048 + h * 64;
#pragma unroll
  for (int i = 0; i < 16; ++i) {
    int n = i * 4 + rr;
    t[n][cc] = src[(size_t)(n0 + n) * 3072 + cc];
  }
  __syncthreads();
  u16* dst = vt + (size_t)bh * 64 * SEQ;
#pragma unroll
  for (int i = 0; i < 16; ++i) {
    int d = i * 4 + rr;
    dst[(size_t)d * SEQ + n0 + cc] = t[cc][d];
  }
}

// ------------- GEMM v2: BK=64, XOR chunk-swizzled LDS (conflict-free b128) -------------
// C(MxN) = A(MxK,bf16) @ Bt(NxK,bf16)^T + bias. Tile (MT*32) x 128.
// 16 barriers for K=1024 (vs 32 at BK=32); 32 MFMA per barrier.
// mode 0: write bf16, scale cols<1024 by QSCALE.  mode 1: write fp32.
template <int MT>
__global__ void __launch_bounds__(256) gemm_kernel(const u16* __restrict__ A,
                                                   const u16* __restrict__ Bt,
                                                   const float* __restrict__ bias,
                                                   u16* __restrict__ outb,
                                                   float* __restrict__ outf,
                                                   int N, int K, int mode) {
  constexpr int R = MT * 32;
  __shared__ alignas(16) u16 As[R * 64];
  __shared__ alignas(16) u16 Bs[128 * 64];
  int tid = threadIdx.x;
  int lane = tid & 63, wave = tid >> 6;
  int wm = wave >> 1, wn = wave & 1;
  int qr = lane & 15, quad = lane >> 4;
  size_t rowA = (size_t)blockIdx.y * R;
  size_t rowB = (size_t)blockIdx.x * 128;

  // staging: each ASYNC16 covers 8 rows (lane>>3) x 8 chunk slots (lane&7),
  // source chunk = slot ^ (row&7)  (row&7 == lane>>3 since row blocks are 8-aligned)
  int klr = lane >> 3;
  int kcs = (lane & 7) ^ klr;

  f32x4 acc[MT][4];
#pragma unroll
  for (int mt = 0; mt < MT; ++mt)
#pragma unroll
    for (int nt = 0; nt < 4; ++nt) acc[mt][nt] = (f32x4){0.f, 0.f, 0.f, 0.f};

  for (int k0 = 0; k0 < K; k0 += 64) {
    // stage A rows [wave*(R/4), +R/4), 8 rows per instruction
#pragma unroll
    for (int i = 0; i < R / 32; ++i) {
      int ar = wave * (R / 4) + i * 8;
      ASYNC16(A + (rowA + ar + klr) * K + k0 + kcs * 8, &As[ar * 64 + lane * 8]);
    }
    // stage B rows [wave*32, +32)
#pragma unroll
    for (int i = 0; i < 4; ++i) {
      int br = wave * 32 + i * 8;
      ASYNC16(Bt + (rowB + br + klr) * K + k0 + kcs * 8, &Bs[br * 64 + lane * 8]);
    }
    __syncthreads();
#pragma unroll
    for (int ks = 0; ks < 2; ++ks) {
      bf16x8 af[MT], bfr[4];
#pragma unroll
      for (int mt = 0; mt < MT; ++mt) {
        int row = wm * (MT * 16) + mt * 16 + qr;
        af[mt] = *(const bf16x8*)&As[row * 64 + (((ks * 4 + quad) ^ (qr & 7)) << 3)];
      }
#pragma unroll
      for (int nt = 0; nt < 4; ++nt) {
        int row = wn * 64 + nt * 16 + qr;
        bfr[nt] = *(const bf16x8*)&Bs[row * 64 + (((ks * 4 + quad) ^ (qr & 7)) << 3)];
      }
#pragma unroll
      for (int mt = 0; mt < MT; ++mt)
#pragma unroll
        for (int nt = 0; nt < 4; ++nt)
          acc[mt][nt] = MFMA16(af[mt], bfr[nt], acc[mt][nt]);
    }
    __syncthreads();
  }

#pragma unroll
  for (int nt = 0; nt < 4; ++nt) {
    int col = (int)rowB + wn * 64 + nt * 16 + qr;
    float bv = bias[col];
#pragma unroll
    for (int mt = 0; mt < MT; ++mt) {
      size_t row = rowA + wm * (MT * 16) + mt * 16 + quad * 4;
#pragma unroll
      for (int r = 0; r < 4; ++r) {
        float v = acc[mt][nt][r] + bv;
        if (mode == 0) {
          if (col < 1024) v *= QSCALE;
          outb[(row + r) * N + col] = f2bf(v);
        } else {
          outf[(row + r) * N + col] = v;
        }
      }
    }
  }
}

// ------------- flash attention v6 (round-8 best): 128 Q rows/block, BK=128 -------------
// K-tile (128x64) + Vt-tile (64x128) DMA'd to LDS (global_load_lds 16B, chunk-XOR
// swizzle), double-buffered: 64KB. One barrier per 128 keys (16 total).
// Two 64-key sub-phases per staged tile share the wave-private P buffer.
// QK^T transposed (A=K, B=Q): lane holds 4 consecutive key-scores of one Q row.
// Denominator on the MFMA pipe via B=ones.
__global__ void __launch_bounds__(256) attn_kernel(const u16* __restrict__ qkv,
                                                   const u16* __restrict__ vt,
                                                   u16* __restrict__ out) {
  __shared__ alignas(16) u16 kbuf[2][128 * 64];
  __shared__ alignas(16) u16 vbuf[2][64 * 128];
  __shared__ alignas(16) u16 pbuf[4][32 * 64];
  int bh = blockIdx.x;
  int b = bh >> 4, h = bh & 15;
  int m0 = blockIdx.y * 128;
  int tid = threadIdx.x;
  int lane = tid & 63, wave = tid >> 6;
  int qr = lane & 15, quad = lane >> 4;

  const u16* kbase = qkv + (size_t)(b * SEQ) * 3072 + 1024 + h * 64;  // K rows, stride 3072
  const u16* vtbase = vt + (size_t)bh * 64 * SEQ;                     // Vt rows, stride 2048
  u16* pw = &pbuf[wave][0];

  int klr = lane >> 3;
  int kcs = (lane & 7) ^ klr;

  // ---- Q fragments (32 rows per wave) ----
  const u16* qbase = qkv + (size_t)(b * SEQ + m0 + wave * 32) * 3072 + h * 64;
  bf16x8 qf[2][2];
#pragma unroll
  for (int mt = 0; mt < 2; ++mt)
#pragma unroll
    for (int ks = 0; ks < 2; ++ks)
      qf[mt][ks] = *(const bf16x8*)&qbase[(size_t)(mt * 16 + qr) * 3072 + ks * 32 + quad * 8];

  const bf16x8 vone = __builtin_bit_cast(bf16x8, (u16x8v)((u16)0x3F80));

  f32x4 o[2][4], l5[2];
#pragma unroll
  for (int mt = 0; mt < 2; ++mt) {
    l5[mt] = (f32x4){0.f, 0.f, 0.f, 0.f};
#pragma unroll
    for (int dt = 0; dt < 4; ++dt) o[mt][dt] = (f32x4){0.f, 0.f, 0.f, 0.f};
  }

  auto stage = [&](int buf, int n0) {
#pragma unroll
    for (int i = 0; i < 4; ++i) {
      int kr = wave * 32 + i * 8 + klr;
      ASYNC16(kbase + (size_t)(n0 + kr) * 3072 + kcs * 8,
              &kbuf[buf][(wave * 32 + i * 8) * 64 + lane * 8]);
    }
#pragma unroll
    for (int i = 0; i < 4; ++i) {
      int vr = wave * 16 + i * 4 + (lane >> 4);
      int vcs = ((lane & 7) ^ (vr & 7)) | (lane & 8);
      ASYNC16(vtbase + (size_t)vr * 2048 + n0 + vcs * 8,
              &vbuf[buf][(wave * 16 + i * 4) * 128 + lane * 8]);
    }
  };

  stage(0, 0);

  for (int t = 0; t < 16; ++t) {
    int cur = t & 1;
    __syncthreads();  // staging of buf[cur] complete; prev reads of buf[cur^1] done

    if (t + 1 < 16) stage(cur ^ 1, (t + 1) * 128);

#pragma unroll
    for (int sp = 0; sp < 2; ++sp) {
      const u16* kb = &kbuf[cur][sp * 64 * 64];
      const u16* vb = &vbuf[cur][0];

      // S^T = K.Q^T : lane holds m = qr, n = nt*16 + quad*4 + r (4 consecutive keys)
      bf16x8 kf[4][2];
#pragma unroll
      for (int nt = 0; nt < 4; ++nt)
#pragma unroll
        for (int ks = 0; ks < 2; ++ks)
          kf[nt][ks] =
              *(const bf16x8*)&kb[(nt * 16 + qr) * 64 + (((ks * 4 + quad) ^ (qr & 7)) << 3)];

#pragma unroll
      for (int mt = 0; mt < 2; ++mt)
#pragma unroll
        for (int nt = 0; nt < 4; ++nt) {
          f32x4 z = (f32x4){0.f, 0.f, 0.f, 0.f};
          z = MFMA16(kf[nt][0], qf[mt][0], z);
          z = MFMA16(kf[nt][1], qf[mt][1], z);
          float p0 = __builtin_amdgcn_exp2f(z[0]);
          float p1 = __builtin_amdgcn_exp2f(z[1]);
          float p2 = __builtin_amdgcn_exp2f(z[2]);
          float p3 = __builtin_amdgcn_exp2f(z[3]);
          uint2 pk;
          pk.x = cvt2(p0, p1);
          pk.y = cvt2(p2, p3);
          int nb = nt * 16 + quad * 4;
          int addr = (mt * 16 + qr) * 64 + ((((nb >> 3) ^ (qr & 7)) << 3) | (nb & 7));
          *(uint2*)&pw[addr] = pk;
        }

      bf16x8 vf[4][2];
#pragma unroll
      for (int dt = 0; dt < 4; ++dt)
#pragma unroll
        for (int ks = 0; ks < 2; ++ks)
          vf[dt][ks] = *(const bf16x8*)&vb[(dt * 16 + qr) * 128 +
                                           ((sp * 8 + ((ks * 4 + quad) ^ (qr & 7))) << 3)];

      bf16x8 pf[2][2];
#pragma unroll
      for (int mt = 0; mt < 2; ++mt)
#pragma unroll
        for (int ks = 0; ks < 2; ++ks)
          pf[mt][ks] =
              *(const bf16x8*)&pw[(mt * 16 + qr) * 64 + (((ks * 4 + quad) ^ (qr & 7)) << 3)];

#pragma unroll
      for (int mt = 0; mt < 2; ++mt) {
#pragma unroll
        for (int dt = 0; dt < 4; ++dt) {
          o[mt][dt] = MFMA16(pf[mt][0], vf[dt][0], o[mt][dt]);
          o[mt][dt] = MFMA16(pf[mt][1], vf[dt][1], o[mt][dt]);
        }
        l5[mt] = MFMA16(pf[mt][0], vone, l5[mt]);
        l5[mt] = MFMA16(pf[mt][1], vone, l5[mt]);
      }
    }
  }

  // l5[mt][r] already holds the denominator for exactly the rows this lane stores.
  u16* obase = out + (size_t)(b * SEQ + m0 + wave * 32) * CH + h * 64;
#pragma unroll
  for (int mt = 0; mt < 2; ++mt)
#pragma unroll
    for (int r = 0; r < 4; ++r) {
      float inv = 1.0f / l5[mt][r];
#pragma unroll
      for (int dt = 0; dt < 4; ++dt)
        obase[(size_t)(mt * 16 + quad * 4 + r) * CH + dt * 16 + qr] = f2bf(o[mt][dt][r] * inv);
    }
}

extern "C" void kernel_launch(void* const* d_in, const int* in_sizes, int n_in,
                              void* d_out, int out_size, void* d_ws, size_t ws_size,
                              hipStream_t stream) {
  const float* x      = (const float*)d_in[0];
  const float* qkv_w  = (const float*)d_in[1];
  const float* qkv_b  = (const float*)d_in[2];
  const float* proj_w = (const float*)d_in[3];
  const float* proj_b = (const float*)d_in[4];
  float* out = (float*)d_out;

  char* w = (char*)d_ws;
  // ws layout (42 MB):
  //   qkv_bf : 4096x3072 bf16 = 25165824 B
  //   xb     : 4096x1024 bf16 =  8388608 B  (reused as attn_bf after gemm1)
  //   wprojt : 1024x1024 bf16 =  2097152 B
  //   wqkvt  : 3072x1024 bf16 (6 MB) region sized 8 MB, reused as vt (B,H,D,N)
  u16* qkv_bf = (u16*)w;
  u16* xb     = (u16*)(w + 25165824);
  u16* wprojt = (u16*)(w + 25165824 + 8388608);
  u16* wqkvt  = (u16*)(w + 25165824 + 8388608 + 2097152);
  u16* attn_bf = xb;
  u16* vt      = wqkvt;

  prep_kernel<<<5120, 256, 0, stream>>>(x, qkv_w, proj_w, xb, wqkvt, wprojt);
  // qkv = x @ qkv_w + b  (bf16 out; Q cols pre-scaled by log2e/8)
  gemm_kernel<4><<<dim3(24, 32), 256, 0, stream>>>(xb, wqkvt, qkv_b, qkv_bf, nullptr, 3072, 1024, 0);
  tv_kernel<<<dim3(32, 32), 256, 0, stream>>>(qkv_bf, vt);
  attn_kernel<<<dim3(32, 16), 256, 0, stream>>>(qkv_bf, vt, attn_bf);
  // out = attn @ proj_w + b (fp32); 64x128 tile -> 512 blocks
  gemm_kernel<2><<<dim3(8, 64), 256, 0, stream>>>(attn_bf, wprojt, proj_b, nullptr, out, 1024, 1024, 1);
}

// Round 12
// 196.482 us; speedup vs baseline: 1.1241x; 1.0016x over previous
//
#include <hip/hip_runtime.h>
#include <cstdint>
#include <cstddef>

typedef __bf16 bf16x8 __attribute__((ext_vector_type(8)));
typedef __bf16 bf16x2v __attribute__((ext_vector_type(2)));
typedef unsigned short u16;
typedef u16 u16x8v __attribute__((ext_vector_type(8)));
typedef float  f32x4  __attribute__((ext_vector_type(4)));
typedef unsigned int u32;

#define MFMA16(a, b, c) __builtin_amdgcn_mfma_f32_16x16x32_bf16((a), (b), (c), 0, 0, 0)
#define ASYNC16(g, l)                                                              \
  __builtin_amdgcn_global_load_lds(                                                \
      (const __attribute__((address_space(1))) unsigned int*)(g),                  \
      (__attribute__((address_space(3))) unsigned int*)(l), 16, 0, 0)

__device__ __forceinline__ u16 f2bf(float f) {
  unsigned u = __builtin_bit_cast(unsigned, f);
  u += 0x7fffu + ((u >> 16) & 1u);
  return (u16)(u >> 16);
}

// packed fp32x2 -> bf16x2 (RNE) via hardware cvt
__device__ __forceinline__ u32 cvt2(float a, float b) {
  bf16x2v t;
  t[0] = (__bf16)a;
  t[1] = (__bf16)b;
  return __builtin_bit_cast(u32, t);
}

#define SEQ 2048
#define CH  1024
#define NH  16
#define HD  64
// log2(e) / sqrt(64) folded into stored Q so softmax uses exp2
#define QSCALE 0.18033688011112042f

// ------------- fused prep: cast x + transpose-cast qkv_w + proj_w -------------
__global__ void __launch_bounds__(256) prep_kernel(const float* __restrict__ x,
                                                   const float* __restrict__ qkv_w,
                                                   const float* __restrict__ proj_w,
                                                   u16* __restrict__ xb,
                                                   u16* __restrict__ wqkvt,
                                                   u16* __restrict__ wprojt) {
  __shared__ u16 t[64][68];
  int bx = blockIdx.x;
  int tx = threadIdx.x;
  if (bx < 4096) {
    int i = bx * 256 + tx;
    float4 v = ((const float4*)x)[i];
    ushort4 o;
    o.x = f2bf(v.x); o.y = f2bf(v.y); o.z = f2bf(v.z); o.w = f2bf(v.w);
    ((ushort4*)xb)[i] = o;
    return;
  }
  const float* in; u16* out; int R, C, c0, r0;
  if (bx < 4096 + 768) {
    int i = bx - 4096;
    in = qkv_w; out = wqkvt; R = 1024; C = 3072;
    c0 = (i % 48) * 64; r0 = (i / 48) * 64;
  } else {
    int i = bx - 4864;
    in = proj_w; out = wprojt; R = 1024; C = 1024;
    c0 = (i % 16) * 64; r0 = (i / 16) * 64;
  }
  int rr = tx >> 6, cc = tx & 63;
#pragma unroll
  for (int i = 0; i < 16; ++i) {
    int r = i * 4 + rr;
    t[r][cc] = f2bf(in[(size_t)(r0 + r) * C + c0 + cc]);
  }
  __syncthreads();
#pragma unroll
  for (int i = 0; i < 16; ++i) {
    int r = i * 4 + rr;
    out[(size_t)(c0 + r) * R + r0 + cc] = t[cc][r];
  }
}

// ------------- GEMM v3: BK=64, XOR-swizzled LDS, TRUE double-buffered staging -------------
// Stage-after-barrier pattern (validated in attn): DMA of tile t+1 flies during
// compute of tile t, drained only at the next barrier. One barrier per K-iteration.
// mode 0 (qkv): cols<1024 scaled+bf16->qk (stride 2048); cols 1024..2047 bf16->qk;
//               cols>=2048 are V -> written TRANSPOSED to vtout (ushort4 per lane).
// mode 1 (proj): fp32 -> outf.
template <int MT>
__global__ void __launch_bounds__(256) gemm_kernel(const u16* __restrict__ A,
                                                   const u16* __restrict__ Bt,
                                                   const float* __restrict__ bias,
                                                   u16* __restrict__ qk,
                                                   u16* __restrict__ vtout,
                                                   float* __restrict__ outf,
                                                   int K, int mode) {
  constexpr int R = MT * 32;
  __shared__ alignas(16) u16 As[2][R * 64];
  __shared__ alignas(16) u16 Bs[2][128 * 64];
  int tid = threadIdx.x;
  int lane = tid & 63, wave = tid >> 6;
  int wm = wave >> 1, wn = wave & 1;
  int qr = lane & 15, quad = lane >> 4;
  size_t rowA = (size_t)blockIdx.y * R;
  size_t rowB = (size_t)blockIdx.x * 128;

  int klr = lane >> 3;
  int kcs = (lane & 7) ^ klr;

  f32x4 acc[MT][4];
#pragma unroll
  for (int mt = 0; mt < MT; ++mt)
#pragma unroll
    for (int nt = 0; nt < 4; ++nt) acc[mt][nt] = (f32x4){0.f, 0.f, 0.f, 0.f};

  auto stage = [&](int buf, int k0) {
#pragma unroll
    for (int i = 0; i < R / 32; ++i) {
      int ar = wave * (R / 4) + i * 8;
      ASYNC16(A + (rowA + ar + klr) * K + k0 + kcs * 8, &As[buf][ar * 64 + lane * 8]);
    }
#pragma unroll
    for (int i = 0; i < 4; ++i) {
      int br = wave * 32 + i * 8;
      ASYNC16(Bt + (rowB + br + klr) * K + k0 + kcs * 8, &Bs[buf][br * 64 + lane * 8]);
    }
  };

  stage(0, 0);
  int iters = K >> 6;
  for (int t = 0; t < iters; ++t) {
    int cur = t & 1;
    __syncthreads();  // drains DMA into buf[cur]; all waves done reading buf[cur^1]
    if (t + 1 < iters) stage(cur ^ 1, (t + 1) * 64);
#pragma unroll
    for (int ks = 0; ks < 2; ++ks) {
      bf16x8 af[MT], bfr[4];
#pragma unroll
      for (int mt = 0; mt < MT; ++mt) {
        int row = wm * (MT * 16) + mt * 16 + qr;
        af[mt] = *(const bf16x8*)&As[cur][row * 64 + (((ks * 4 + quad) ^ (qr & 7)) << 3)];
      }
#pragma unroll
      for (int nt = 0; nt < 4; ++nt) {
        int row = wn * 64 + nt * 16 + qr;
        bfr[nt] = *(const bf16x8*)&Bs[cur][row * 64 + (((ks * 4 + quad) ^ (qr & 7)) << 3)];
      }
#pragma unroll
      for (int mt = 0; mt < MT; ++mt)
#pragma unroll
        for (int nt = 0; nt < 4; ++nt)
          acc[mt][nt] = MFMA16(af[mt], bfr[nt], acc[mt][nt]);
    }
    __syncthreads();  // reads of buf[cur] done before next iter's stage overwrites
  }

#pragma unroll
  for (int nt = 0; nt < 4; ++nt) {
    int col = (int)rowB + wn * 64 + nt * 16 + qr;
    float bv = bias[col];
#pragma unroll
    for (int mt = 0; mt < MT; ++mt) {
      size_t row = rowA + wm * (MT * 16) + mt * 16 + quad * 4;
      if (mode == 1) {
#pragma unroll
        for (int r = 0; r < 4; ++r)
          outf[(row + r) * 1024 + col] = acc[mt][nt][r] + bv;
      } else if (col < 2048) {
        // Q (scaled) and K -> packed QK buffer, stride 2048
#pragma unroll
        for (int r = 0; r < 4; ++r) {
          float v = acc[mt][nt][r] + bv;
          if (col < 1024) v *= QSCALE;
          qk[(row + r) * 2048 + col] = f2bf(v);
        }
      } else {
        // V -> transposed layout vt[bh][d][n]; 4 accumulator rows = consecutive n
        int c = col - 2048;
        int bh_ = ((int)(row >> 11)) * 16 + (c >> 6);
        int d = c & 63;
        int n = (int)(row & 2047);
        ushort4 pv;
        pv.x = f2bf(acc[mt][nt][0] + bv);
        pv.y = f2bf(acc[mt][nt][1] + bv);
        pv.z = f2bf(acc[mt][nt][2] + bv);
        pv.w = f2bf(acc[mt][nt][3] + bv);
        *(ushort4*)&vtout[(size_t)bh_ * 131072 + d * 2048 + n] = pv;
      }
    }
  }
}

// ------------- flash attention v6 (round-8/11 best), QK stride 2048 -------------
// K-tile (128x64) + Vt-tile (64x128) DMA'd to LDS (global_load_lds 16B, chunk-XOR
// swizzle), double-buffered: 64KB. One barrier per 128 keys (16 total).
// QK^T transposed (A=K, B=Q); denominator on the MFMA pipe via B=ones.
__global__ void __launch_bounds__(256) attn_kernel(const u16* __restrict__ qkbuf,
                                                   const u16* __restrict__ vt,
                                                   u16* __restrict__ out) {
  __shared__ alignas(16) u16 kbuf[2][128 * 64];
  __shared__ alignas(16) u16 vbuf[2][64 * 128];
  __shared__ alignas(16) u16 pbuf[4][32 * 64];
  int bh = blockIdx.x;
  int b = bh >> 4, h = bh & 15;
  int m0 = blockIdx.y * 128;
  int tid = threadIdx.x;
  int lane = tid & 63, wave = tid >> 6;
  int qr = lane & 15, quad = lane >> 4;

  const u16* kbase = qkbuf + (size_t)(b * SEQ) * 2048 + 1024 + h * 64;  // K rows, stride 2048
  const u16* vtbase = vt + (size_t)bh * 64 * SEQ;                       // Vt rows, stride 2048
  u16* pw = &pbuf[wave][0];

  int klr = lane >> 3;
  int kcs = (lane & 7) ^ klr;

  // ---- Q fragments (32 rows per wave) ----
  const u16* qbase = qkbuf + (size_t)(b * SEQ + m0 + wave * 32) * 2048 + h * 64;
  bf16x8 qf[2][2];
#pragma unroll
  for (int mt = 0; mt < 2; ++mt)
#pragma unroll
    for (int ks = 0; ks < 2; ++ks)
      qf[mt][ks] = *(const bf16x8*)&qbase[(size_t)(mt * 16 + qr) * 2048 + ks * 32 + quad * 8];

  const bf16x8 vone = __builtin_bit_cast(bf16x8, (u16x8v)((u16)0x3F80));

  f32x4 o[2][4], l5[2];
#pragma unroll
  for (int mt = 0; mt < 2; ++mt) {
    l5[mt] = (f32x4){0.f, 0.f, 0.f, 0.f};
#pragma unroll
    for (int dt = 0; dt < 4; ++dt) o[mt][dt] = (f32x4){0.f, 0.f, 0.f, 0.f};
  }

  auto stage = [&](int buf, int n0) {
#pragma unroll
    for (int i = 0; i < 4; ++i) {
      int kr = wave * 32 + i * 8 + klr;
      ASYNC16(kbase + (size_t)(n0 + kr) * 2048 + kcs * 8,
              &kbuf[buf][(wave * 32 + i * 8) * 64 + lane * 8]);
    }
#pragma unroll
    for (int i = 0; i < 4; ++i) {
      int vr = wave * 16 + i * 4 + (lane >> 4);
      int vcs = ((lane & 7) ^ (vr & 7)) | (lane & 8);
      ASYNC16(vtbase + (size_t)vr * 2048 + n0 + vcs * 8,
              &vbuf[buf][(wave * 16 + i * 4) * 128 + lane * 8]);
    }
  };

  stage(0, 0);

  for (int t = 0; t < 16; ++t) {
    int cur = t & 1;
    __syncthreads();

    if (t + 1 < 16) stage(cur ^ 1, (t + 1) * 128);

#pragma unroll
    for (int sp = 0; sp < 2; ++sp) {
      const u16* kb = &kbuf[cur][sp * 64 * 64];
      const u16* vb = &vbuf[cur][0];

      bf16x8 kf[4][2];
#pragma unroll
      for (int nt = 0; nt < 4; ++nt)
#pragma unroll
        for (int ks = 0; ks < 2; ++ks)
          kf[nt][ks] =
              *(const bf16x8*)&kb[(nt * 16 + qr) * 64 + (((ks * 4 + quad) ^ (qr & 7)) << 3)];

#pragma unroll
      for (int mt = 0; mt < 2; ++mt)
#pragma unroll
        for (int nt = 0; nt < 4; ++nt) {
          f32x4 z = (f32x4){0.f, 0.f, 0.f, 0.f};
          z = MFMA16(kf[nt][0], qf[mt][0], z);
          z = MFMA16(kf[nt][1], qf[mt][1], z);
          float p0 = __builtin_amdgcn_exp2f(z[0]);
          float p1 = __builtin_amdgcn_exp2f(z[1]);
          float p2 = __builtin_amdgcn_exp2f(z[2]);
          float p3 = __builtin_amdgcn_exp2f(z[3]);
          uint2 pk;
          pk.x = cvt2(p0, p1);
          pk.y = cvt2(p2, p3);
          int nb = nt * 16 + quad * 4;
          int addr = (mt * 16 + qr) * 64 + ((((nb >> 3) ^ (qr & 7)) << 3) | (nb & 7));
          *(uint2*)&pw[addr] = pk;
        }

      bf16x8 vf[4][2];
#pragma unroll
      for (int dt = 0; dt < 4; ++dt)
#pragma unroll
        for (int ks = 0; ks < 2; ++ks)
          vf[dt][ks] = *(const bf16x8*)&vb[(dt * 16 + qr) * 128 +
                                           ((sp * 8 + ((ks * 4 + quad) ^ (qr & 7))) << 3)];

      bf16x8 pf[2][2];
#pragma unroll
      for (int mt = 0; mt < 2; ++mt)
#pragma unroll
        for (int ks = 0; ks < 2; ++ks)
          pf[mt][ks] =
              *(const bf16x8*)&pw[(mt * 16 + qr) * 64 + (((ks * 4 + quad) ^ (qr & 7)) << 3)];

#pragma unroll
      for (int mt = 0; mt < 2; ++mt) {
#pragma unroll
        for (int dt = 0; dt < 4; ++dt) {
          o[mt][dt] = MFMA16(pf[mt][0], vf[dt][0], o[mt][dt]);
          o[mt][dt] = MFMA16(pf[mt][1], vf[dt][1], o[mt][dt]);
        }
        l5[mt] = MFMA16(pf[mt][0], vone, l5[mt]);
        l5[mt] = MFMA16(pf[mt][1], vone, l5[mt]);
      }
    }
  }

  u16* obase = out + (size_t)(b * SEQ + m0 + wave * 32) * CH + h * 64;
#pragma unroll
  for (int mt = 0; mt < 2; ++mt)
#pragma unroll
    for (int r = 0; r < 4; ++r) {
      float inv = 1.0f / l5[mt][r];
#pragma unroll
      for (int dt = 0; dt < 4; ++dt)
        obase[(size_t)(mt * 16 + quad * 4 + r) * CH + dt * 16 + qr] = f2bf(o[mt][dt][r] * inv);
    }
}

extern "C" void kernel_launch(void* const* d_in, const int* in_sizes, int n_in,
                              void* d_out, int out_size, void* d_ws, size_t ws_size,
                              hipStream_t stream) {
  const float* x      = (const float*)d_in[0];
  const float* qkv_w  = (const float*)d_in[1];
  const float* qkv_b  = (const float*)d_in[2];
  const float* proj_w = (const float*)d_in[3];
  const float* proj_b = (const float*)d_in[4];
  float* out = (float*)d_out;

  char* w = (char*)d_ws;
  // ws layout (42 MB):
  //   qkqk  : 4096x2048 bf16 (Q scaled | K, stride 2048) = 16777216 B
  //   xb    : 4096x1024 bf16 = 8388608 B (reused as attn_bf after gemm1)
  //   wprojt: 1024x1024 bf16 = 2097152 B
  //   wqkvt : 3072x1024 bf16 = 6291456 B
  //   vt    : (B*H)x64x2048 bf16 = 8388608 B (written directly by gemm1 epilogue)
  u16* qkqk   = (u16*)w;
  u16* xb     = (u16*)(w + 16777216);
  u16* wprojt = (u16*)(w + 25165824);
  u16* wqkvt  = (u16*)(w + 27262976);
  u16* vt     = (u16*)(w + 33554432);
  u16* attn_bf = xb;

  prep_kernel<<<5120, 256, 0, stream>>>(x, qkv_w, proj_w, xb, wqkvt, wprojt);
  // qkv = x @ qkv_w + b; Q scaled; QK -> qkqk (stride 2048), V -> vt (transposed)
  gemm_kernel<4><<<dim3(24, 32), 256, 0, stream>>>(xb, wqkvt, qkv_b, qkqk, vt, nullptr, 1024, 0);
  attn_kernel<<<dim3(32, 16), 256, 0, stream>>>(qkqk, vt, attn_bf);
  // out = attn @ proj_w + b (fp32)
  gemm_kernel<2><<<dim3(8, 64), 256, 0, stream>>>(attn_bf, wprojt, proj_b, nullptr, nullptr, out, 1024, 1);
}